// Round 23
// baseline (3396.721 us; speedup 1.0000x reference)
//
#include <hip/hip_runtime.h>
#include <hip/hip_bf16.h>

#define T_LEN 512
#define NB 64      // batch
#define FB 256     // input features
#define SB 1024    // hidden size
#define NWG 128    // persistent workgroups: (p 0..1) x (sb 0..63), 2 chains each

typedef __attribute__((ext_vector_type(8))) short bf16x8;
typedef __attribute__((ext_vector_type(4))) float f32x4;

#define MFMA(a, b, c) __builtin_amdgcn_mfma_f32_16x16x32_bf16((a), (b), (c), 0, 0, 0)

__device__ __forceinline__ float fast_sigmoid(float z) {
    return 1.f / (1.f + __expf(-z));
}
__device__ __forceinline__ float fast_tanh(float z) {
    return 1.f - 2.f / (1.f + __expf(2.f * z));
}

// device-scope (sc1) 16B fragment load as 2 relaxed agent u64 atomics
__device__ __forceinline__ bf16x8 load_frag_dev(const __hip_bfloat16* p) {
    const unsigned long long* q = (const unsigned long long*)p;
    unsigned long long a = __hip_atomic_load(q,     __ATOMIC_RELAXED, __HIP_MEMORY_SCOPE_AGENT);
    unsigned long long b = __hip_atomic_load(q + 1, __ATOMIC_RELAXED, __HIP_MEMORY_SCOPE_AGENT);
    union { unsigned long long u[2]; bf16x8 v; } r;
    r.u[0] = a; r.u[1] = b;
    return r.v;
}

// ---------------- prep: x -> MFMA A-fragment order, bf16 ----------------
// XAf[t][m(4)][kc(8)][lane*8+e] ; element = x[t][m*16+(l&15)][kc*32+8*(l>>4)+e]
__global__ void xfrag_kernel(const float* __restrict__ x, __hip_bfloat16* __restrict__ xaf) {
    int tid  = blockIdx.x * 256 + threadIdx.x;   // total T*4*8*64 = 1,048,576
    int l    = tid & 63;
    int frag = tid >> 6;                         // t*32 + m*8 + kc
    int kc   = frag & 7;
    int m    = (frag >> 3) & 3;
    int t    = frag >> 5;
    int row  = m * 16 + (l & 15);
    int k0   = kc * 32 + 8 * (l >> 4);
    const float* src = x + ((size_t)(t * NB + row)) * FB + k0;
    __hip_bfloat16* dst = xaf + (size_t)frag * 512 + l * 8;
#pragma unroll
    for (int e = 0; e < 8; ++e) dst[e] = __float2bfloat16(src[e]);
}

// ------------- prep: [Wx;Wh] -> per-(sb,wave) register-load order -------------
// WBf[sb(64)][wv(4)][kcw(10)][g(4)][lane*8+e]
// kc(wv,kcw) = kcw<2 ? wv*2+kcw : 8 + wv*8 + (kcw-2)
// k = kc*32+8*(l>>4)+e ; s = sb*16+(l&15)
__global__ void wfrag_kernel(const float* __restrict__ Wx, const float* __restrict__ Wh,
                             __hip_bfloat16* __restrict__ wbf) {
    int tid  = blockIdx.x * 256 + threadIdx.x;   // total 64*4*10*4*64 = 655,360
    int l    = tid & 63;
    int frag = tid >> 6;                         // ((sb*4+wv)*10+kcw)*4+g
    int g    = frag & 3;
    int kcw  = (frag >> 2) % 10;
    int wv   = (frag / 40) & 3;
    int sb   = frag / 160;
    int kc   = (kcw < 2) ? (wv * 2 + kcw) : (8 + wv * 8 + (kcw - 2));
    int s    = sb * 16 + (l & 15);
    int k0   = kc * 32 + 8 * (l >> 4);
    __hip_bfloat16* dst = wbf + (size_t)frag * 512 + l * 8;
#pragma unroll
    for (int e = 0; e < 8; ++e) {
        int k = k0 + e;
        float v = (k < FB) ? Wx[((size_t)g * FB + k) * SB + s]
                           : Wh[((size_t)g * SB + (k - FB)) * SB + s];
        dst[e] = __float2bfloat16(v);
    }
}

// ---------------- persistent LSTM kernel: 2 phase-shifted chains per WG ----------------
// Batch rows are INDEPENDENT sequences -> 4 independent 16-row LSTMs (ng=0..3).
// WG b = (p = b>>6, sb = b&63) hosts chain A (ng=2p) and chain B (ng=2p+1), same
// sb -> same weights. Each chain's flag-propagate / poll-observe L3 trips hide
// under the OTHER chain's compute+drain phase.
// hfrag layout (bf16 units): chain ng base = ng*65536; slot (t&3)*16384;
// fragment f (k-chunk, 0..31) at f*512; element = h_local[l&15][f*32+8*(l>>4)+e].
// (r22's NaN: fragment stride was 256 not 512, and only 2 chain regions for 4
//  chains -- p=0/p=1 collided. Both fixed; design otherwise identical.)
__global__ __launch_bounds__(256, 1) void lstm_persist(
    const __hip_bfloat16* __restrict__ xaf,   // [512][4][8][512]
    const __hip_bfloat16* __restrict__ wbf,   // [64][4][10][4][512]
    const float* __restrict__ bias,           // [4][1024]
    __hip_bfloat16* __restrict__ hfrag,       // [4 chains][4 slots][32][512]
    float* __restrict__ cbuf,                 // [64][1024] fp32 c-state
    float* __restrict__ out,                  // [512][64][1024]
    unsigned int* __restrict__ flag,          // [512][128][4]: per-WG, per-chain
    int t0, int nsteps, int use_sync)
{
    __shared__ float part[4 * 16 * 4 * 17];   // 17,408 B: ((wv*16+n)*4+g)*17 + sc
    const int tid = threadIdx.x;
    const int wv  = tid >> 6;
    const int l   = tid & 63;
    const int p   = blockIdx.x >> 6;          // chain pair 0..1
    const int sb  = blockIdx.x & 63;
    const int lr  = l & 15;
    const int lg  = l >> 4;
    const int ngA = 2 * p, ngB = 2 * p + 1;

    // poll: lane l -> producer WG (p, wv*16 + (l&15))  [4-way broadcast per chain]
    const int fbase = (p * 64 + wv * 16 + (l & 15)) * 4;

    // gate-phase mapping (ALL 256 threads): thread -> (row gn, col sc), 1 element
    const int gn = tid >> 4;                  // 0..15 local row
    const int sc = tid & 15;                  // 0..15 local col

    // ---- one-time: weight fragments (shared by both chains; stream from L2)
    bf16x8 wf[40];
    {
        const __hip_bfloat16* wp = wbf + ((size_t)(sb * 4 + wv) * 40) * 512 + l * 8;
#pragma unroll
        for (int i = 0; i < 40; ++i) wf[i] = *reinterpret_cast<const bf16x8*>(wp + (size_t)i * 512);
    }
    // ---- one-time: bias (col-only) + c-state for both chains
    float br[4];
#pragma unroll
    for (int g = 0; g < 4; ++g) br[g] = bias[g * SB + sb * 16 + sc];
    float cregA = cbuf[(ngA * 16 + gn) * SB + sb * 16 + sc];
    float cregB = cbuf[(ngB * 16 + gn) * SB + sb * 16 + sc];

    // h-store halfword offset within a slot (same for both chains)
    const int k8   = 16 * (sb & 1) + sc;      // 0..31: k within chunk sb>>1
    const int lane = (k8 >> 3) * 16 + gn;
    const int hoff = (sb >> 1) * 512 + lane * 8 + (k8 & 7);

    f32x4 accA[4], accB[4];
    // ---- prologue: x-parts of first step for both chains
#pragma unroll
    for (int g = 0; g < 4; ++g) { accA[g] = (f32x4){0,0,0,0}; accB[g] = (f32x4){0,0,0,0}; }
    {
        const __hip_bfloat16* xs = xaf + (size_t)t0 * 16384;
#pragma unroll
        for (int j = 0; j < 2; ++j) {
            int kc = wv * 2 + j;
            bf16x8 aA = *reinterpret_cast<const bf16x8*>(xs + (size_t)(ngA * 8 + kc) * 512 + l * 8);
            bf16x8 aB = *reinterpret_cast<const bf16x8*>(xs + (size_t)(ngB * 8 + kc) * 512 + l * 8);
#pragma unroll
            for (int g = 0; g < 4; ++g) {
                accA[g] = MFMA(aA, wf[j * 4 + g], accA[g]);
                accB[g] = MFMA(aB, wf[j * 4 + g], accB[g]);
            }
        }
    }

    for (int tt = 0; tt < nsteps; ++tt) {
        const int t = t0 + tt;
        const __hip_bfloat16* hsA = hfrag + (size_t)ngA * 65536 + (size_t)(t & 3) * 16384;
        const __hip_bfloat16* hsB = hfrag + (size_t)ngB * 65536 + (size_t)(t & 3) * 16384;

        // ======== PHASE A ========
        if (use_sync && tt > 0) {
            const unsigned int* f1 = flag + (size_t)(t - 1) * 512;
            for (;;) {
                unsigned a = __hip_atomic_load(&f1[fbase], __ATOMIC_RELAXED, __HIP_MEMORY_SCOPE_AGENT);
                if (__all(a != 0)) break;
            }
            asm volatile("" ::: "memory");
        }
        // h-loads A (8 sc1 fragment loads, batched) + MFMAs
#pragma unroll
        for (int j = 0; j < 8; ++j) {
            bf16x8 a = load_frag_dev(hsA + (size_t)(wv * 8 + j) * 512 + l * 8);
#pragma unroll
            for (int g = 0; g < 4; ++g) accA[g] = MFMA(a, wf[(2 + j) * 4 + g], accA[g]);
        }
        // reduce A
#pragma unroll
        for (int g = 0; g < 4; ++g)
#pragma unroll
            for (int i = 0; i < 4; ++i)
                part[((wv * 16 + lg * 4 + i) * 4 + g) * 17 + lr] = accA[g][i];
        __syncthreads();
        // gates A (all 256 threads, 1 element)
        float hvA;
        {
            float z[4];
#pragma unroll
            for (int g = 0; g < 4; ++g) {
                float s = 0.f;
#pragma unroll
                for (int w2 = 0; w2 < 4; ++w2) s += part[((w2 * 16 + gn) * 4 + g) * 17 + sc];
                z[g] = s + br[g];
            }
            float ig = fast_sigmoid(z[0]);
            float fg = fast_sigmoid(z[1]);
            float gg = fast_tanh(z[2]);
            float og = fast_sigmoid(z[3]);
            float c  = fg * cregA + ig * gg;
            hvA      = og * fast_tanh(c);
            cregA    = c;
            unsigned short hu = __bfloat16_as_ushort(__float2bfloat16(hvA));
            unsigned short* hd = reinterpret_cast<unsigned short*>(
                hfrag + (size_t)ngA * 65536 + (size_t)((t + 1) & 3) * 16384) + hoff;
            __hip_atomic_store(hd, hu, __ATOMIC_RELAXED, __HIP_MEMORY_SCOPE_AGENT);
        }
        if (use_sync) {
            __syncthreads();   // drains A h-stores
            if (tid == 0)
                __hip_atomic_store(&flag[((size_t)t * 128 + blockIdx.x) * 4], 1u,
                                   __ATOMIC_RELAXED, __HIP_MEMORY_SCOPE_AGENT);
        }
        out[(size_t)t * (NB * SB) + (size_t)(ngA * 16 + gn) * SB + sb * 16 + sc] = hvA;

        // ======== PHASE B ========
        if (use_sync && tt > 0) {
            const unsigned int* f1 = flag + (size_t)(t - 1) * 512;
            for (;;) {
                unsigned a = __hip_atomic_load(&f1[fbase + 1], __ATOMIC_RELAXED, __HIP_MEMORY_SCOPE_AGENT);
                if (__all(a != 0)) break;
            }
            asm volatile("" ::: "memory");
        }
#pragma unroll
        for (int j = 0; j < 8; ++j) {
            bf16x8 a = load_frag_dev(hsB + (size_t)(wv * 8 + j) * 512 + l * 8);
#pragma unroll
            for (int g = 0; g < 4; ++g) accB[g] = MFMA(a, wf[(2 + j) * 4 + g], accB[g]);
        }
        // WAR guard for part: coop path is covered by the arrive-A barrier
        if (!use_sync) __syncthreads();
#pragma unroll
        for (int g = 0; g < 4; ++g)
#pragma unroll
            for (int i = 0; i < 4; ++i)
                part[((wv * 16 + lg * 4 + i) * 4 + g) * 17 + lr] = accB[g][i];
        __syncthreads();
        float hvB;
        {
            float z[4];
#pragma unroll
            for (int g = 0; g < 4; ++g) {
                float s = 0.f;
#pragma unroll
                for (int w2 = 0; w2 < 4; ++w2) s += part[((w2 * 16 + gn) * 4 + g) * 17 + sc];
                z[g] = s + br[g];
            }
            float ig = fast_sigmoid(z[0]);
            float fg = fast_sigmoid(z[1]);
            float gg = fast_tanh(z[2]);
            float og = fast_sigmoid(z[3]);
            float c  = fg * cregB + ig * gg;
            hvB      = og * fast_tanh(c);
            cregB    = c;
            unsigned short hu = __bfloat16_as_ushort(__float2bfloat16(hvB));
            unsigned short* hd = reinterpret_cast<unsigned short*>(
                hfrag + (size_t)ngB * 65536 + (size_t)((t + 1) & 3) * 16384) + hoff;
            __hip_atomic_store(hd, hu, __ATOMIC_RELAXED, __HIP_MEMORY_SCOPE_AGENT);
        }
        if (use_sync) {
            __syncthreads();   // drains B h-stores
            if (tid == 0)
                __hip_atomic_store(&flag[((size_t)t * 128 + blockIdx.x) * 4 + 1], 1u,
                                   __ATOMIC_RELAXED, __HIP_MEMORY_SCOPE_AGENT);
        }
        out[(size_t)t * (NB * SB) + (size_t)(ngB * 16 + gn) * SB + sb * 16 + sc] = hvB;

        // ---- x-tails for next step (both chains; h-independent)
        if (tt + 1 < nsteps) {
#pragma unroll
            for (int g = 0; g < 4; ++g) { accA[g] = (f32x4){0,0,0,0}; accB[g] = (f32x4){0,0,0,0}; }
            const __hip_bfloat16* xs = xaf + (size_t)(t + 1) * 16384;
#pragma unroll
            for (int j = 0; j < 2; ++j) {
                int kc = wv * 2 + j;
                bf16x8 aA = *reinterpret_cast<const bf16x8*>(xs + (size_t)(ngA * 8 + kc) * 512 + l * 8);
                bf16x8 aB = *reinterpret_cast<const bf16x8*>(xs + (size_t)(ngB * 8 + kc) * 512 + l * 8);
#pragma unroll
                for (int g = 0; g < 4; ++g) {
                    accA[g] = MFMA(aA, wf[j * 4 + g], accA[g]);
                    accB[g] = MFMA(aB, wf[j * 4 + g], accB[g]);
                }
            }
        }
    }

    // ---- persist c-state (needed for the per-step fallback path)
    cbuf[(ngA * 16 + gn) * SB + sb * 16 + sc] = cregA;
    cbuf[(ngB * 16 + gn) * SB + sb * 16 + sc] = cregB;
}

extern "C" void kernel_launch(void* const* d_in, const int* in_sizes, int n_in,
                              void* d_out, int out_size, void* d_ws, size_t ws_size,
                              hipStream_t stream) {
    const float* x  = (const float*)d_in[0];   // [512][64][256]
    const float* Wx = (const float*)d_in[1];   // [4][256][1024]
    const float* Wh = (const float*)d_in[2];   // [4][1024][1024]
    const float* b  = (const float*)d_in[3];   // [4][1024]
    float* out = (float*)d_out;                // [512][64][1024]

    char* ws = (char*)d_ws;
    __hip_bfloat16* xaf   = (__hip_bfloat16*)ws;                 // 16,777,216 B
    __hip_bfloat16* wbf   = (__hip_bfloat16*)(ws + 16777216);    // 10,485,760 B
    __hip_bfloat16* hfrag = (__hip_bfloat16*)(ws + 27262976);    //    524,288 B (4ch x 4 slots)
    float*          cbuf  = (float*)(ws + 27787264);             //    262,144 B
    unsigned int*   flag  = (unsigned int*)(ws + 28049408);      //  1,048,576 B

    hipLaunchKernelGGL(xfrag_kernel, dim3(4096), dim3(256), 0, stream, x, xaf);
    hipLaunchKernelGGL(wfrag_kernel, dim3(2560), dim3(256), 0, stream, Wx, Wh, wbf);
    hipMemsetAsync(hfrag, 0, 524288, stream);   // h[-1] = 0 (all chains, all slots)
    hipMemsetAsync(cbuf, 0, 262144, stream);    // c[-1] = 0
    hipMemsetAsync(flag, 0, 1048576, stream);   // per-step per-WG per-chain flags

    const __hip_bfloat16* p_xaf = xaf;
    const __hip_bfloat16* p_wbf = wbf;
    const float* p_bias = b;
    __hip_bfloat16* p_hfrag = hfrag;
    float* p_cbuf = cbuf;
    float* p_out = out;
    unsigned int* p_flag = flag;
    int z0 = 0, ns = T_LEN, us = 1;
    void* args[] = {&p_xaf, &p_wbf, &p_bias, &p_hfrag, &p_cbuf, &p_out, &p_flag, &z0, &ns, &us};
    hipError_t err = hipLaunchCooperativeKernel((void*)lstm_persist, dim3(NWG), dim3(256),
                                                args, 0, stream);
    if (err != hipSuccess) {
        // fallback: per-step plain launches (kernel boundaries order memory)
        for (int t = 0; t < T_LEN; ++t) {
            hipLaunchKernelGGL(lstm_persist, dim3(NWG), dim3(256), 0, stream,
                               xaf, wbf, b, hfrag, cbuf, out, flag, t, 1, 0);
        }
    }
}

// Round 24
// 1418.498 us; speedup vs baseline: 2.3946x; 2.3946x over previous
//
#include <hip/hip_runtime.h>
#include <hip/hip_bf16.h>

#define T_LEN 512
#define NB 64      // batch
#define FB 256     // input features
#define SB 1024    // hidden size
#define NWG 256    // persistent workgroups: (ng 0..3) x (sb 0..63)

typedef __attribute__((ext_vector_type(8))) short bf16x8;
typedef __attribute__((ext_vector_type(4))) float f32x4;

#define MFMA(a, b, c) __builtin_amdgcn_mfma_f32_16x16x32_bf16((a), (b), (c), 0, 0, 0)

__device__ __forceinline__ float fast_sigmoid(float z) {
    return 1.f / (1.f + __expf(-z));
}
__device__ __forceinline__ float fast_tanh(float z) {
    return 1.f - 2.f / (1.f + __expf(2.f * z));
}

// device-scope (sc1) 16B fragment load as 2 relaxed agent u64 atomics
__device__ __forceinline__ bf16x8 load_frag_dev(const __hip_bfloat16* p) {
    const unsigned long long* q = (const unsigned long long*)p;
    unsigned long long a = __hip_atomic_load(q,     __ATOMIC_RELAXED, __HIP_MEMORY_SCOPE_AGENT);
    unsigned long long b = __hip_atomic_load(q + 1, __ATOMIC_RELAXED, __HIP_MEMORY_SCOPE_AGENT);
    union { unsigned long long u[2]; bf16x8 v; } r;
    r.u[0] = a; r.u[1] = b;
    return r.v;
}

// ---------------- prep: x -> MFMA A-fragment order, bf16 ----------------
__global__ void xfrag_kernel(const float* __restrict__ x, __hip_bfloat16* __restrict__ xaf) {
    int tid  = blockIdx.x * 256 + threadIdx.x;   // total T*4*8*64 = 1,048,576
    int l    = tid & 63;
    int frag = tid >> 6;                         // t*32 + m*8 + kc
    int kc   = frag & 7;
    int m    = (frag >> 3) & 3;
    int t    = frag >> 5;
    int row  = m * 16 + (l & 15);
    int k0   = kc * 32 + 8 * (l >> 4);
    const float* src = x + ((size_t)(t * NB + row)) * FB + k0;
    __hip_bfloat16* dst = xaf + (size_t)frag * 512 + l * 8;
#pragma unroll
    for (int e = 0; e < 8; ++e) dst[e] = __float2bfloat16(src[e]);
}

// ------------- prep: [Wx;Wh] -> per-(sb,wave) register-load order -------------
__global__ void wfrag_kernel(const float* __restrict__ Wx, const float* __restrict__ Wh,
                             __hip_bfloat16* __restrict__ wbf) {
    int tid  = blockIdx.x * 256 + threadIdx.x;   // total 64*4*10*4*64 = 655,360
    int l    = tid & 63;
    int frag = tid >> 6;                         // ((sb*4+wv)*10+kcw)*4+g
    int g    = frag & 3;
    int kcw  = (frag >> 2) % 10;
    int wv   = (frag / 40) & 3;
    int sb   = frag / 160;
    int kc   = (kcw < 2) ? (wv * 2 + kcw) : (8 + wv * 8 + (kcw - 2));
    int s    = sb * 16 + (l & 15);
    int k0   = kc * 32 + 8 * (l >> 4);
    __hip_bfloat16* dst = wbf + (size_t)frag * 512 + l * 8;
#pragma unroll
    for (int e = 0; e < 8; ++e) {
        int k = k0 + e;
        float v = (k < FB) ? Wx[((size_t)g * FB + k) * SB + s]
                           : Wh[((size_t)g * SB + (k - FB)) * SB + s];
        dst[e] = __float2bfloat16(v);
    }
}

// ---- init: sentinel-fill hfrag slots 1..511 (bytes 511*131072; uint4 fill) ----
__global__ void sentinit_kernel(uint4* __restrict__ p) {
    p[blockIdx.x * 256 + threadIdx.x] =
        (uint4){0x7FC07FC0u, 0x7FC07FC0u, 0x7FC07FC0u, 0x7FC07FC0u};
}

// ============ DATA-SYNC persistent kernel (512 unique h slots) ============
// r21 structure; flags/arrive-barrier REMOVED. h slot per step (written once,
// sentinel-initialized once per launch). Consumer retry-loads its 8 fragments
// until NO 16-bit lane == 0x7FC0 (|h|<1 -> sentinel unreachable in data; u16
// stores are atomic, check is per-u16). The poll IS the load: serial path =
// gates -> u16 sc1 store -> L3 -> consumer observes. One barrier/step (reduce);
// part[] parity-double-buffered (WAR guard for the removed arrive barrier).
__global__ __launch_bounds__(256, 1) void lstm_ds(
    const __hip_bfloat16* __restrict__ xaf,   // [512][4][8][512]
    const __hip_bfloat16* __restrict__ wbf,   // [64][4][10][4][512]
    const float* __restrict__ bias,           // [4][1024]
    __hip_bfloat16* __restrict__ hfrag,       // [512 slots][32][4][512]
    float* __restrict__ cbuf,                 // [64][1024] fp32 c-state
    float* __restrict__ out,                  // [512][64][1024]
    int t0, int nsteps)
{
    __shared__ float part[2][4 * 16 * 4 * 17];  // 2 x 17,408 B (step parity)
    const int tid = threadIdx.x;
    const int wv  = tid >> 6;
    const int l   = tid & 63;
    const int ng  = blockIdx.x >> 6;          // row-group 0..3 (16 rows)
    const int sb  = blockIdx.x & 63;
    const int lr  = l & 15;
    const int lg  = l >> 4;

    // gate-phase mapping (ALL 256 threads): thread -> (row gn, col sc)
    const int gn = tid >> 4;
    const int sc = tid & 15;

    // ---- one-time: weight fragments (stream from L2 every step)
    bf16x8 wf[40];
    {
        const __hip_bfloat16* wp = wbf + ((size_t)(sb * 4 + wv) * 40) * 512 + l * 8;
#pragma unroll
        for (int i = 0; i < 40; ++i) wf[i] = *reinterpret_cast<const bf16x8*>(wp + (size_t)i * 512);
    }
    // ---- one-time: bias + c-state
    float br[4];
#pragma unroll
    for (int g = 0; g < 4; ++g) br[g] = bias[g * SB + sb * 16 + sc];
    float creg = cbuf[(ng * 16 + gn) * SB + sb * 16 + sc];

    // h-store halfword offset within a slot
    const int k8   = 16 * (sb & 1) + sc;
    const int lane = (k8 >> 3) * 16 + gn;
    const size_t hoff = (size_t)((sb >> 1) * 4 + ng) * 512 + lane * 8 + (k8 & 7);

    f32x4 acc[4];
#pragma unroll
    for (int g = 0; g < 4; ++g) acc[g] = (f32x4){0.f, 0.f, 0.f, 0.f};
    {
        const __hip_bfloat16* xs = xaf + (size_t)t0 * 16384;
#pragma unroll
        for (int j = 0; j < 2; ++j) {
            int kc = wv * 2 + j;
            bf16x8 a = *reinterpret_cast<const bf16x8*>(xs + (size_t)(ng * 8 + kc) * 512 + l * 8);
#pragma unroll
            for (int g = 0; g < 4; ++g) acc[g] = MFMA(a, wf[j * 4 + g], acc[g]);
        }
    }

    for (int tt = 0; tt < nsteps; ++tt) {
        const int t  = t0 + tt;
        const int pb = t & 1;

        // ---- retry-load h fragments from slot t until sentinel-free
        const __hip_bfloat16* hs = hfrag + (size_t)t * 65536;
        unsigned long long v[16];
        for (;;) {
#pragma unroll
            for (int j = 0; j < 8; ++j) {
                const unsigned long long* q = reinterpret_cast<const unsigned long long*>(
                    hs + (size_t)((wv * 8 + j) * 4 + ng) * 512 + l * 8);
                v[2 * j]     = __hip_atomic_load(q,     __ATOMIC_RELAXED, __HIP_MEMORY_SCOPE_AGENT);
                v[2 * j + 1] = __hip_atomic_load(q + 1, __ATOMIC_RELAXED, __HIP_MEMORY_SCOPE_AGENT);
            }
            bool ok = true;
#pragma unroll
            for (int k = 0; k < 16; ++k) {
                unsigned lo = (unsigned)v[k], hi = (unsigned)(v[k] >> 32);
                ok = ok && ((lo & 0xFFFFu) != 0x7FC0u) && ((lo >> 16) != 0x7FC0u)
                        && ((hi & 0xFFFFu) != 0x7FC0u) && ((hi >> 16) != 0x7FC0u);
            }
            if (__all(ok)) break;
        }

        // ---- h-part MFMAs straight from the verified registers
#pragma unroll
        for (int j = 0; j < 8; ++j) {
            union { unsigned long long u[2]; bf16x8 a; } ua;
            ua.u[0] = v[2 * j];
            ua.u[1] = v[2 * j + 1];
#pragma unroll
            for (int g = 0; g < 4; ++g) acc[g] = MFMA(ua.a, wf[(2 + j) * 4 + g], acc[g]);
        }

        // ---- cross-wave K-reduce (parity-double-buffered)
#pragma unroll
        for (int g = 0; g < 4; ++g)
#pragma unroll
            for (int i = 0; i < 4; ++i)
                part[pb][((wv * 16 + lg * 4 + i) * 4 + g) * 17 + lr] = acc[g][i];
        __syncthreads();   // the only barrier per step

        // ---- gates + state update: ALL 256 threads, 1 element
        float hv;
        {
            float z[4];
#pragma unroll
            for (int g = 0; g < 4; ++g) {
                float s = 0.f;
#pragma unroll
                for (int w2 = 0; w2 < 4; ++w2)
                    s += part[pb][((w2 * 16 + gn) * 4 + g) * 17 + sc];
                z[g] = s + br[g];
            }
            float ig = fast_sigmoid(z[0]);
            float fg = fast_sigmoid(z[1]);
            float gg = fast_tanh(z[2]);
            float og = fast_sigmoid(z[3]);
            float c  = fg * creg + ig * gg;
            hv       = og * fast_tanh(c);
            creg     = c;
            // h-store to slot t+1 (no drain, no flag; data self-certifies)
            if (t + 1 < T_LEN) {
                unsigned short hu = __bfloat16_as_ushort(__float2bfloat16(hv));
                unsigned short* hd = reinterpret_cast<unsigned short*>(
                    hfrag + (size_t)(t + 1) * 65536) + hoff;
                __hip_atomic_store(hd, hu, __ATOMIC_RELAXED, __HIP_MEMORY_SCOPE_AGENT);
            }
        }

        // ---- out-store (off the signal path)
        out[(size_t)t * (NB * SB) + (size_t)(ng * 16 + gn) * SB + sb * 16 + sc] = hv;

        // ---- tail: x-part of next step
        if (tt + 1 < nsteps) {
#pragma unroll
            for (int g = 0; g < 4; ++g) acc[g] = (f32x4){0.f, 0.f, 0.f, 0.f};
            const __hip_bfloat16* xs = xaf + (size_t)(t + 1) * 16384;
#pragma unroll
            for (int j = 0; j < 2; ++j) {
                int kc = wv * 2 + j;
                bf16x8 a = *reinterpret_cast<const bf16x8*>(xs + (size_t)(ng * 8 + kc) * 512 + l * 8);
#pragma unroll
                for (int g = 0; g < 4; ++g) acc[g] = MFMA(a, wf[j * 4 + g], acc[g]);
            }
        }
    }

    cbuf[(ng * 16 + gn) * SB + sb * 16 + sc] = creg;
}

// ============ FLAG-SYNC fallback kernel (r21 verbatim; small-ws path) ============
__global__ __launch_bounds__(256, 1) void lstm_fl(
    const __hip_bfloat16* __restrict__ xaf,
    const __hip_bfloat16* __restrict__ wbf,
    const float* __restrict__ bias,
    __hip_bfloat16* __restrict__ hfrag,       // [4][32][4][512]
    float* __restrict__ cbuf,
    float* __restrict__ out,
    unsigned int* __restrict__ flag,          // [512][256][2]
    int t0, int nsteps, int use_sync)
{
    __shared__ float part[4 * 16 * 4 * 17];
    const int tid = threadIdx.x;
    const int wv  = tid >> 6;
    const int l   = tid & 63;
    const int ng  = blockIdx.x >> 6;
    const int sb  = blockIdx.x & 63;
    const int lr  = l & 15;
    const int lg  = l >> 4;
    const int fidx = (ng * 64 + wv * 16 + (l & 15)) * 2;
    const int gn = tid >> 4;
    const int sc = tid & 15;

    bf16x8 wf[40];
    {
        const __hip_bfloat16* wp = wbf + ((size_t)(sb * 4 + wv) * 40) * 512 + l * 8;
#pragma unroll
        for (int i = 0; i < 40; ++i) wf[i] = *reinterpret_cast<const bf16x8*>(wp + (size_t)i * 512);
    }
    float br[4];
#pragma unroll
    for (int g = 0; g < 4; ++g) br[g] = bias[g * SB + sb * 16 + sc];
    float creg = cbuf[(ng * 16 + gn) * SB + sb * 16 + sc];
    const int k8   = 16 * (sb & 1) + sc;
    const int lane = (k8 >> 3) * 16 + gn;
    const size_t hoff = (size_t)((sb >> 1) * 4 + ng) * 512 + lane * 8 + (k8 & 7);

    f32x4 acc[4];
#pragma unroll
    for (int g = 0; g < 4; ++g) acc[g] = (f32x4){0.f, 0.f, 0.f, 0.f};
    {
        const __hip_bfloat16* xs = xaf + (size_t)t0 * 16384;
#pragma unroll
        for (int j = 0; j < 2; ++j) {
            int kc = wv * 2 + j;
            bf16x8 a = *reinterpret_cast<const bf16x8*>(xs + (size_t)(ng * 8 + kc) * 512 + l * 8);
#pragma unroll
            for (int g = 0; g < 4; ++g) acc[g] = MFMA(a, wf[j * 4 + g], acc[g]);
        }
    }

    for (int tt = 0; tt < nsteps; ++tt) {
        const int t = t0 + tt;
        if (use_sync && tt > 0) {
            const unsigned int* f1 = flag + (size_t)(t - 1) * 512;
            for (;;) {
                unsigned a = __hip_atomic_load(&f1[fidx], __ATOMIC_RELAXED, __HIP_MEMORY_SCOPE_AGENT);
                if (__all(a != 0)) break;
            }
            asm volatile("" ::: "memory");
        }
        const __hip_bfloat16* hs = hfrag + (size_t)(t & 3) * 65536;
#pragma unroll
        for (int j = 0; j < 8; ++j) {
            int kch = wv * 8 + j;
            bf16x8 a = load_frag_dev(hs + (size_t)(kch * 4 + ng) * 512 + l * 8);
#pragma unroll
            for (int g = 0; g < 4; ++g) acc[g] = MFMA(a, wf[(2 + j) * 4 + g], acc[g]);
        }
#pragma unroll
        for (int g = 0; g < 4; ++g)
#pragma unroll
            for (int i = 0; i < 4; ++i)
                part[((wv * 16 + lg * 4 + i) * 4 + g) * 17 + lr] = acc[g][i];
        __syncthreads();
        float hv;
        {
            float z[4];
#pragma unroll
            for (int g = 0; g < 4; ++g) {
                float s = 0.f;
#pragma unroll
                for (int w2 = 0; w2 < 4; ++w2) s += part[((w2 * 16 + gn) * 4 + g) * 17 + sc];
                z[g] = s + br[g];
            }
            float ig = fast_sigmoid(z[0]);
            float fg = fast_sigmoid(z[1]);
            float gg = fast_tanh(z[2]);
            float og = fast_sigmoid(z[3]);
            float c  = fg * creg + ig * gg;
            hv       = og * fast_tanh(c);
            creg     = c;
            unsigned short hu = __bfloat16_as_ushort(__float2bfloat16(hv));
            unsigned short* hd = reinterpret_cast<unsigned short*>(
                hfrag + (size_t)((t + 1) & 3) * 65536) + hoff;
            __hip_atomic_store(hd, hu, __ATOMIC_RELAXED, __HIP_MEMORY_SCOPE_AGENT);
        }
        if (use_sync) {
            __syncthreads();
            if (tid == 0)
                __hip_atomic_store(&flag[((size_t)t * 256 + blockIdx.x) * 2], 1u,
                                   __ATOMIC_RELAXED, __HIP_MEMORY_SCOPE_AGENT);
        }
        out[(size_t)t * (NB * SB) + (size_t)(ng * 16 + gn) * SB + sb * 16 + sc] = hv;
        if (tt + 1 < nsteps) {
#pragma unroll
            for (int g = 0; g < 4; ++g) acc[g] = (f32x4){0.f, 0.f, 0.f, 0.f};
            const __hip_bfloat16* xs = xaf + (size_t)(t + 1) * 16384;
#pragma unroll
            for (int j = 0; j < 2; ++j) {
                int kc = wv * 2 + j;
                bf16x8 a = *reinterpret_cast<const bf16x8*>(xs + (size_t)(ng * 8 + kc) * 512 + l * 8);
#pragma unroll
                for (int g = 0; g < 4; ++g) acc[g] = MFMA(a, wf[j * 4 + g], acc[g]);
            }
        }
    }
    cbuf[(ng * 16 + gn) * SB + sb * 16 + sc] = creg;
}

extern "C" void kernel_launch(void* const* d_in, const int* in_sizes, int n_in,
                              void* d_out, int out_size, void* d_ws, size_t ws_size,
                              hipStream_t stream) {
    const float* x  = (const float*)d_in[0];   // [512][64][256]
    const float* Wx = (const float*)d_in[1];   // [4][256][1024]
    const float* Wh = (const float*)d_in[2];   // [4][1024][1024]
    const float* b  = (const float*)d_in[3];   // [4][1024]
    float* out = (float*)d_out;                // [512][64][1024]

    char* ws = (char*)d_ws;
    __hip_bfloat16* xaf = (__hip_bfloat16*)ws;                 // 16,777,216 B
    __hip_bfloat16* wbf = (__hip_bfloat16*)(ws + 16777216);    // 10,485,760 B

    hipLaunchKernelGGL(xfrag_kernel, dim3(4096), dim3(256), 0, stream, x, xaf);
    hipLaunchKernelGGL(wfrag_kernel, dim3(2560), dim3(256), 0, stream, Wx, Wh, wbf);

    const size_t NEED = 16777216ULL + 10485760ULL + 67108864ULL + 262144ULL; // 94,633,984

    if (ws_size >= NEED) {
        // -------- data-sync path: 512 unique h slots, no flags --------
        __hip_bfloat16* hfrag = (__hip_bfloat16*)(ws + 27262976);  // 67,108,864 B
        float*          cbuf  = (float*)(ws + 94371840);           //    262,144 B

        // sentinel-fill slots 1..511 (511*131072 B = 4,186,112 uint4)
        hipLaunchKernelGGL(sentinit_kernel, dim3(16352), dim3(256), 0, stream,
                           (uint4*)(hfrag + 65536));
        hipMemsetAsync(hfrag, 0, 131072, stream);   // slot 0: h[-1] = 0
        hipMemsetAsync(cbuf, 0, 262144, stream);    // c[-1] = 0

        const __hip_bfloat16* p_xaf = xaf;
        const __hip_bfloat16* p_wbf = wbf;
        const float* p_bias = b;
        __hip_bfloat16* p_hfrag = hfrag;
        float* p_cbuf = cbuf;
        float* p_out = out;
        int z0 = 0, ns = T_LEN;
        void* args[] = {&p_xaf, &p_wbf, &p_bias, &p_hfrag, &p_cbuf, &p_out, &z0, &ns};
        hipError_t err = hipLaunchCooperativeKernel((void*)lstm_ds, dim3(NWG), dim3(256),
                                                    args, 0, stream);
        if (err != hipSuccess) {
            // per-step launches: sentinel mechanism works across kernel boundaries
            for (int t = 0; t < T_LEN; ++t) {
                hipLaunchKernelGGL(lstm_ds, dim3(NWG), dim3(256), 0, stream,
                                   xaf, wbf, b, hfrag, cbuf, out, t, 1);
            }
        }
    } else {
        // -------- flag-sync path (r21, proven 1267 us) --------
        __hip_bfloat16* hfrag = (__hip_bfloat16*)(ws + 27262976);  //    524,288 B
        float*          cbuf  = (float*)(ws + 27787264);           //    262,144 B
        unsigned int*   flag  = (unsigned int*)(ws + 28049408);    //  1,048,576 B

        hipMemsetAsync(hfrag, 0, 524288, stream);
        hipMemsetAsync(cbuf, 0, 262144, stream);
        hipMemsetAsync(flag, 0, 1048576, stream);

        const __hip_bfloat16* p_xaf = xaf;
        const __hip_bfloat16* p_wbf = wbf;
        const float* p_bias = b;
        __hip_bfloat16* p_hfrag = hfrag;
        float* p_cbuf = cbuf;
        float* p_out = out;
        unsigned int* p_flag = flag;
        int z0 = 0, ns = T_LEN, us = 1;
        void* args[] = {&p_xaf, &p_wbf, &p_bias, &p_hfrag, &p_cbuf, &p_out, &p_flag, &z0, &ns, &us};
        hipError_t err = hipLaunchCooperativeKernel((void*)lstm_fl, dim3(NWG), dim3(256),
                                                    args, 0, stream);
        if (err != hipSuccess) {
            for (int t = 0; t < T_LEN; ++t) {
                hipLaunchKernelGGL(lstm_fl, dim3(NWG), dim3(256), 0, stream,
                                   xaf, wbf, b, hfrag, cbuf, out, flag, t, 1, 0);
            }
        }
    }
}

// Round 25
// 1403.003 us; speedup vs baseline: 2.4210x; 1.0110x over previous
//
#include <hip/hip_runtime.h>
#include <hip/hip_bf16.h>

#define T_LEN 512
#define NB 64      // batch
#define FB 256     // input features
#define SB 1024    // hidden size
#define NWG 256    // persistent workgroups: (ng 0..3) x (sb 0..63)

typedef __attribute__((ext_vector_type(8))) short bf16x8;
typedef __attribute__((ext_vector_type(4))) float f32x4;

#define MFMA(a, b, c) __builtin_amdgcn_mfma_f32_16x16x32_bf16((a), (b), (c), 0, 0, 0)

__device__ __forceinline__ float fast_sigmoid(float z) {
    return 1.f / (1.f + __expf(-z));
}
__device__ __forceinline__ float fast_tanh(float z) {
    return 1.f - 2.f / (1.f + __expf(2.f * z));
}

// device-scope (sc1) 16B fragment load as 2 relaxed agent u64 atomics
__device__ __forceinline__ bf16x8 load_frag_dev(const __hip_bfloat16* p) {
    const unsigned long long* q = (const unsigned long long*)p;
    unsigned long long a = __hip_atomic_load(q,     __ATOMIC_RELAXED, __HIP_MEMORY_SCOPE_AGENT);
    unsigned long long b = __hip_atomic_load(q + 1, __ATOMIC_RELAXED, __HIP_MEMORY_SCOPE_AGENT);
    union { unsigned long long u[2]; bf16x8 v; } r;
    r.u[0] = a; r.u[1] = b;
    return r.v;
}

// ---------------- prep: x -> MFMA A-fragment order, bf16 ----------------
__global__ void xfrag_kernel(const float* __restrict__ x, __hip_bfloat16* __restrict__ xaf) {
    int tid  = blockIdx.x * 256 + threadIdx.x;   // total T*4*8*64 = 1,048,576
    int l    = tid & 63;
    int frag = tid >> 6;                         // t*32 + m*8 + kc
    int kc   = frag & 7;
    int m    = (frag >> 3) & 3;
    int t    = frag >> 5;
    int row  = m * 16 + (l & 15);
    int k0   = kc * 32 + 8 * (l >> 4);
    const float* src = x + ((size_t)(t * NB + row)) * FB + k0;
    __hip_bfloat16* dst = xaf + (size_t)frag * 512 + l * 8;
#pragma unroll
    for (int e = 0; e < 8; ++e) dst[e] = __float2bfloat16(src[e]);
}

// ------------- prep: [Wx;Wh] -> per-(sb,wave) register-load order -------------
__global__ void wfrag_kernel(const float* __restrict__ Wx, const float* __restrict__ Wh,
                             __hip_bfloat16* __restrict__ wbf) {
    int tid  = blockIdx.x * 256 + threadIdx.x;   // total 64*4*10*4*64 = 655,360
    int l    = tid & 63;
    int frag = tid >> 6;                         // ((sb*4+wv)*10+kcw)*4+g
    int g    = frag & 3;
    int kcw  = (frag >> 2) % 10;
    int wv   = (frag / 40) & 3;
    int sb   = frag / 160;
    int kc   = (kcw < 2) ? (wv * 2 + kcw) : (8 + wv * 8 + (kcw - 2));
    int s    = sb * 16 + (l & 15);
    int k0   = kc * 32 + 8 * (l >> 4);
    __hip_bfloat16* dst = wbf + (size_t)frag * 512 + l * 8;
#pragma unroll
    for (int e = 0; e < 8; ++e) {
        int k = k0 + e;
        float v = (k < FB) ? Wx[((size_t)g * FB + k) * SB + s]
                           : Wh[((size_t)g * SB + (k - FB)) * SB + s];
        dst[e] = __float2bfloat16(v);
    }
}

// ---- init: sentinel-fill hfrag slots 1..511 (511*131072 B as uint4) ----
__global__ void sentinit_kernel(uint4* __restrict__ p) {
    p[blockIdx.x * 256 + threadIdx.x] =
        (uint4){0x7FC07FC0u, 0x7FC07FC0u, 0x7FC07FC0u, 0x7FC07FC0u};
}

// ========== HYBRID persistent kernel: issued-flag + sentinel-verified data ==========
// 512 unique h slots (one-time sentinel init). Producer: gates -> sc1 u16
// h-store -> tid0 relaxed flag ("issued"; program-order after its own h-store).
// NO arrive barrier, NO vmcnt drain. Consumer: cheap 16-producer flag spin
// (r21's poll), then loads its 8 fragments and retries while any u16 ==
// 0x7FC0 (|h|<1 -> sentinel unreachable; u16 stores atomic). Retries are rare:
// producer h-stores issue within ~100cy of the flag, flag propagation ~500cy.
// One barrier/step (reduce); part[] parity-double-buffered.
__global__ __launch_bounds__(256, 1) void lstm_hy(
    const __hip_bfloat16* __restrict__ xaf,   // [512][4][8][512]
    const __hip_bfloat16* __restrict__ wbf,   // [64][4][10][4][512]
    const float* __restrict__ bias,           // [4][1024]
    __hip_bfloat16* __restrict__ hfrag,       // [512 slots][32][4][512]
    float* __restrict__ cbuf,                 // [64][1024] fp32 c-state
    float* __restrict__ out,                  // [512][64][1024]
    unsigned int* __restrict__ flag,          // [512][256][2]
    int t0, int nsteps, int use_sync)
{
    __shared__ float part[2][4 * 16 * 4 * 17];  // 2 x 17,408 B (step parity)
    const int tid = threadIdx.x;
    const int wv  = tid >> 6;
    const int l   = tid & 63;
    const int ng  = blockIdx.x >> 6;          // row-group 0..3 (16 rows)
    const int sb  = blockIdx.x & 63;
    const int lr  = l & 15;
    const int lg  = l >> 4;

    // flag poll: lane l -> producer WG (ng, wv*16 + (l&15))  [4-way broadcast]
    const int fidx = (ng * 64 + wv * 16 + (l & 15)) * 2;

    // gate-phase mapping (ALL 256 threads): thread -> (row gn, col sc)
    const int gn = tid >> 4;
    const int sc = tid & 15;

    // ---- one-time: weight fragments (stream from L2 every step)
    bf16x8 wf[40];
    {
        const __hip_bfloat16* wp = wbf + ((size_t)(sb * 4 + wv) * 40) * 512 + l * 8;
#pragma unroll
        for (int i = 0; i < 40; ++i) wf[i] = *reinterpret_cast<const bf16x8*>(wp + (size_t)i * 512);
    }
    // ---- one-time: bias + c-state
    float br[4];
#pragma unroll
    for (int g = 0; g < 4; ++g) br[g] = bias[g * SB + sb * 16 + sc];
    float creg = cbuf[(ng * 16 + gn) * SB + sb * 16 + sc];

    // h-store halfword offset within a slot
    const int k8   = 16 * (sb & 1) + sc;
    const int lane = (k8 >> 3) * 16 + gn;
    const size_t hoff = (size_t)((sb >> 1) * 4 + ng) * 512 + lane * 8 + (k8 & 7);

    f32x4 acc[4];
#pragma unroll
    for (int g = 0; g < 4; ++g) acc[g] = (f32x4){0.f, 0.f, 0.f, 0.f};
    {
        const __hip_bfloat16* xs = xaf + (size_t)t0 * 16384;
#pragma unroll
        for (int j = 0; j < 2; ++j) {
            int kc = wv * 2 + j;
            bf16x8 a = *reinterpret_cast<const bf16x8*>(xs + (size_t)(ng * 8 + kc) * 512 + l * 8);
#pragma unroll
            for (int g = 0; g < 4; ++g) acc[g] = MFMA(a, wf[j * 4 + g], acc[g]);
        }
    }

    for (int tt = 0; tt < nsteps; ++tt) {
        const int t  = t0 + tt;
        const int pb = t & 1;

        // ---- cheap flag spin: my 16 producers ISSUED their step-(t-1) stores
        if (use_sync && tt > 0) {
            const unsigned int* f1 = flag + (size_t)(t - 1) * 512;
            for (;;) {
                unsigned a = __hip_atomic_load(&f1[fidx], __ATOMIC_RELAXED, __HIP_MEMORY_SCOPE_AGENT);
                if (__all(a != 0)) break;
            }
            asm volatile("" ::: "memory");
        }

        // ---- load h fragments from slot t; sentinel-verify (retry rare)
        const __hip_bfloat16* hs = hfrag + (size_t)t * 65536;
        unsigned long long v[16];
        for (;;) {
#pragma unroll
            for (int j = 0; j < 8; ++j) {
                const unsigned long long* q = reinterpret_cast<const unsigned long long*>(
                    hs + (size_t)((wv * 8 + j) * 4 + ng) * 512 + l * 8);
                v[2 * j]     = __hip_atomic_load(q,     __ATOMIC_RELAXED, __HIP_MEMORY_SCOPE_AGENT);
                v[2 * j + 1] = __hip_atomic_load(q + 1, __ATOMIC_RELAXED, __HIP_MEMORY_SCOPE_AGENT);
            }
            bool ok = true;
#pragma unroll
            for (int k = 0; k < 16; ++k) {
                unsigned lo = (unsigned)v[k], hi = (unsigned)(v[k] >> 32);
                ok = ok && ((lo & 0xFFFFu) != 0x7FC0u) && ((lo >> 16) != 0x7FC0u)
                        && ((hi & 0xFFFFu) != 0x7FC0u) && ((hi >> 16) != 0x7FC0u);
            }
            if (__all(ok)) break;
        }

        // ---- h-part MFMAs straight from the verified registers
#pragma unroll
        for (int j = 0; j < 8; ++j) {
            union { unsigned long long u[2]; bf16x8 a; } ua;
            ua.u[0] = v[2 * j];
            ua.u[1] = v[2 * j + 1];
#pragma unroll
            for (int g = 0; g < 4; ++g) acc[g] = MFMA(ua.a, wf[(2 + j) * 4 + g], acc[g]);
        }

        // ---- cross-wave K-reduce (parity-double-buffered)
#pragma unroll
        for (int g = 0; g < 4; ++g)
#pragma unroll
            for (int i = 0; i < 4; ++i)
                part[pb][((wv * 16 + lg * 4 + i) * 4 + g) * 17 + lr] = acc[g][i];
        __syncthreads();   // the only barrier per step

        // ---- gates + state update: ALL 256 threads, 1 element
        float hv;
        {
            float z[4];
#pragma unroll
            for (int g = 0; g < 4; ++g) {
                float s = 0.f;
#pragma unroll
                for (int w2 = 0; w2 < 4; ++w2)
                    s += part[pb][((w2 * 16 + gn) * 4 + g) * 17 + sc];
                z[g] = s + br[g];
            }
            float ig = fast_sigmoid(z[0]);
            float fg = fast_sigmoid(z[1]);
            float gg = fast_tanh(z[2]);
            float og = fast_sigmoid(z[3]);
            float c  = fg * creg + ig * gg;
            hv       = og * fast_tanh(c);
            creg     = c;
            // h-store to slot t+1 (no drain); tid0's flag follows ITS store in
            // program order -- consumers sentinel-verify the rest
            if (t + 1 < T_LEN) {
                unsigned short hu = __bfloat16_as_ushort(__float2bfloat16(hv));
                unsigned short* hd = reinterpret_cast<unsigned short*>(
                    hfrag + (size_t)(t + 1) * 65536) + hoff;
                __hip_atomic_store(hd, hu, __ATOMIC_RELAXED, __HIP_MEMORY_SCOPE_AGENT);
            }
            if (use_sync && tid == 0)
                __hip_atomic_store(&flag[((size_t)t * 256 + blockIdx.x) * 2], 1u,
                                   __ATOMIC_RELAXED, __HIP_MEMORY_SCOPE_AGENT);
        }

        // ---- out-store (off the signal path)
        out[(size_t)t * (NB * SB) + (size_t)(ng * 16 + gn) * SB + sb * 16 + sc] = hv;

        // ---- tail: x-part of next step
        if (tt + 1 < nsteps) {
#pragma unroll
            for (int g = 0; g < 4; ++g) acc[g] = (f32x4){0.f, 0.f, 0.f, 0.f};
            const __hip_bfloat16* xs = xaf + (size_t)(t + 1) * 16384;
#pragma unroll
            for (int j = 0; j < 2; ++j) {
                int kc = wv * 2 + j;
                bf16x8 a = *reinterpret_cast<const bf16x8*>(xs + (size_t)(ng * 8 + kc) * 512 + l * 8);
#pragma unroll
                for (int g = 0; g < 4; ++g) acc[g] = MFMA(a, wf[j * 4 + g], acc[g]);
            }
        }
    }

    cbuf[(ng * 16 + gn) * SB + sb * 16 + sc] = creg;
}

extern "C" void kernel_launch(void* const* d_in, const int* in_sizes, int n_in,
                              void* d_out, int out_size, void* d_ws, size_t ws_size,
                              hipStream_t stream) {
    const float* x  = (const float*)d_in[0];   // [512][64][256]
    const float* Wx = (const float*)d_in[1];   // [4][256][1024]
    const float* Wh = (const float*)d_in[2];   // [4][1024][1024]
    const float* b  = (const float*)d_in[3];   // [4][1024]
    float* out = (float*)d_out;                // [512][64][1024]

    char* ws = (char*)d_ws;
    __hip_bfloat16* xaf   = (__hip_bfloat16*)ws;                 // 16,777,216 B
    __hip_bfloat16* wbf   = (__hip_bfloat16*)(ws + 16777216);    // 10,485,760 B
    __hip_bfloat16* hfrag = (__hip_bfloat16*)(ws + 27262976);    // 67,108,864 B (512 slots)
    float*          cbuf  = (float*)(ws + 94371840);             //    262,144 B
    unsigned int*   flag  = (unsigned int*)(ws + 94633984);      //  1,048,576 B
    // total: 95,682,560 B

    hipLaunchKernelGGL(xfrag_kernel, dim3(4096), dim3(256), 0, stream, x, xaf);
    hipLaunchKernelGGL(wfrag_kernel, dim3(2560), dim3(256), 0, stream, Wx, Wh, wbf);
    // sentinel-fill slots 1..511 (511*131072 B = 4,186,112 uint4)
    hipLaunchKernelGGL(sentinit_kernel, dim3(16352), dim3(256), 0, stream,
                       (uint4*)(hfrag + 65536));
    hipMemsetAsync(hfrag, 0, 131072, stream);   // slot 0: h[-1] = 0
    hipMemsetAsync(cbuf, 0, 262144, stream);    // c[-1] = 0
    hipMemsetAsync(flag, 0, 1048576, stream);   // per-step per-WG flags

    const __hip_bfloat16* p_xaf = xaf;
    const __hip_bfloat16* p_wbf = wbf;
    const float* p_bias = b;
    __hip_bfloat16* p_hfrag = hfrag;
    float* p_cbuf = cbuf;
    float* p_out = out;
    unsigned int* p_flag = flag;
    int z0 = 0, ns = T_LEN, us = 1;
    void* args[] = {&p_xaf, &p_wbf, &p_bias, &p_hfrag, &p_cbuf, &p_out, &p_flag, &z0, &ns, &us};
    hipError_t err = hipLaunchCooperativeKernel((void*)lstm_hy, dim3(NWG), dim3(256),
                                                args, 0, stream);
    if (err != hipSuccess) {
        // fallback: per-step plain launches (kernel boundaries order memory;
        // flag spin skipped, sentinel check passes first try on settled data)
        for (int t = 0; t < T_LEN; ++t) {
            hipLaunchKernelGGL(lstm_hy, dim3(NWG), dim3(256), 0, stream,
                               xaf, wbf, b, hfrag, cbuf, out, flag, t, 1, 0);
        }
    }
}